// Round 9
// baseline (113.186 us; speedup 1.0000x reference)
//
#include <hip/hip_runtime.h>

#define Bv_ 8
#define LQ 128
#define LK 256
#define Dv 32
#define ET 32
#define Hh 8
#define NH 64

// Exact type returned by __builtin_amdgcn_cvt_pkrtz on this toolchain.
typedef __fp16 h2 __attribute__((ext_vector_type(2)));

static __device__ __forceinline__ h2 bch(unsigned u) {
    union { unsigned u; h2 h; } c; c.u = u; return c.h;
}
static __device__ __forceinline__ unsigned pack2(float lo, float hi) {
    union { h2 h; unsigned u; } c;
    c.h = __builtin_amdgcn_cvt_pkrtz(lo, hi);
    return c.u;
}
static __device__ __forceinline__ unsigned short h16(float x) {
    union { __fp16 h; unsigned short u; } c; c.h = (__fp16)x; return c.u;
}
static __device__ __forceinline__ float dot2(h2 a, h2 b, float c) {
#if __has_builtin(__builtin_amdgcn_fdot2)
    return __builtin_amdgcn_fdot2(a, b, c, false);
#else
    return fmaf((float)a.x, (float)b.x, fmaf((float)a.y, (float)b.y, c));
#endif
}

// ---------------------------------------------------------------------------
// Kernel 1: prep (896 blocks x 256) -- unchanged from R8
// ---------------------------------------------------------------------------
__global__ __launch_bounds__(256) void prep_kernel(
    const float* __restrict__ qtt, const float* __restrict__ ktt,
    const float* __restrict__ value, const int* __restrict__ emb_mask,
    const float* __restrict__ w_time, const float* __restrict__ b_time,
    const float* __restrict__ w_per, const float* __restrict__ b_per,
    const float* __restrict__ vt_w1, const float* __restrict__ vt_b1,
    const float* __restrict__ ln_g, const float* __restrict__ ln_b,
    const float* __restrict__ vt_w2, const float* __restrict__ vt_b2,
    const float* __restrict__ wq, const float* __restrict__ bq,
    const float* __restrict__ wk, const float* __restrict__ bk,
    unsigned* __restrict__ A2g, unsigned* __restrict__ B2g,
    unsigned* __restrict__ M2g,
    float* __restrict__ qe, float* __restrict__ ke)
{
    const int t = threadIdx.x;
    const int blk = blockIdx.x;

    if (blk < 512) {
        __shared__ float vrow[4][Dv];
        __shared__ float hrow[4][NH];
        __shared__ float sha[4][Dv], shb[4][Dv], shm[4][Dv];
        const int w = t >> 6;
        const int l = t & 63;
        const int row = blk * 4 + w;           // global (b,k) row

        if (l < Dv) vrow[w][l] = value[row * Dv + l];
        __syncthreads();

        float h = vt_b1[l];
        #pragma unroll
        for (int d = 0; d < Dv; ++d) h += vrow[w][d] * vt_w1[d * NH + l];

        float s = h;
        #pragma unroll
        for (int off = 32; off > 0; off >>= 1) s += __shfl_xor(s, off);
        const float mu = s * (1.0f / NH);
        const float dc = h - mu;
        float vs = dc * dc;
        #pragma unroll
        for (int off = 32; off > 0; off >>= 1) vs += __shfl_xor(vs, off);
        const float rs = rsqrtf(vs * (1.0f / NH) + 1e-5f);
        hrow[w][l] = fmaxf(dc * rs * ln_g[l] + ln_b[l], 0.0f);
        __syncthreads();

        if (l < Dv) {
            float dval = vt_b2[l];
            #pragma unroll
            for (int j = 0; j < NH; ++j) dval += hrow[w][j] * vt_w2[j * Dv + l];
            const float mm = (emb_mask[row * Dv + l] != 0) ? 1.0f : 0.0f;
            sha[w][l] = mm * vrow[w][l];
            shb[w][l] = mm * dval;
            shm[w][l] = mm;
        }
        __syncthreads();

        if (t < 192) {                         // pack k-pairs -> f16x2
            const int arr = t >> 6;            // wave-uniform
            const int pr  = (t >> 5) & 1;
            const int d   = t & 31;
            float lo, hi;
            unsigned* dst;
            if (arr == 0)      { lo = sha[2*pr][d]; hi = sha[2*pr+1][d]; dst = A2g; }
            else if (arr == 1) { lo = shb[2*pr][d]; hi = shb[2*pr+1][d]; dst = B2g; }
            else               { lo = shm[2*pr][d]; hi = shm[2*pr+1][d]; dst = M2g; }
            dst[(blk * 2 + pr) * 32 + d] = pack2(lo, hi);
        }
    } else {
        const int idx = blk - 512;
        const int sub = t >> 5;
        const int j = t & 31;
        const int row = idx * 8 + sub;         // 0..3071
        __shared__ float eb[8][ET];

        float tt;
        const float *W, *bias;
        float* outp;
        if (row < Bv_ * LQ) {
            tt = qtt[row]; W = wq; bias = bq; outp = qe + row * ET;
        } else {
            const int r2 = row - Bv_ * LQ;
            tt = ktt[r2]; W = wk; bias = bk; outp = ke + r2 * ET;
        }
        float e;
        if (j == 0) e = tt * w_time[0] + b_time[0];
        else        e = __sinf(tt * w_per[j - 1] + b_per[j - 1]);
        eb[sub][j] = e;
        __syncthreads();

        float o = bias[j];
        #pragma unroll
        for (int i = 0; i < ET; ++i) o += eb[sub][i] * W[i * ET + j];
        outp[j] = o;
    }
}

// ---------------------------------------------------------------------------
// Kernel 2: attention. 512 blocks = (b, q-tile of 2). Async-staged panels,
// G-on-the-fly (pk_mul), single pre-main barrier, shfl epilogue.
// LDS (uint units, total 14664 u = 58.7 KB):
//   A2s 0..4095 | B2s 4096..8191 | M2s 8192..12287
//   E2s 12288..14399 ([16][132]) | G2s 14400..14663 ([2][132])
// Aliases post-main: REDN=A2s (4096f), REDD=B2s (4096f), XSH=M2s (512f).
// ---------------------------------------------------------------------------
__global__ __launch_bounds__(256, 2) void attn_kernel(
    const float* __restrict__ qtt, const float* __restrict__ ktt,
    const float* __restrict__ w_decay,
    const unsigned* __restrict__ A2g, const unsigned* __restrict__ B2g,
    const unsigned* __restrict__ M2g,
    const float* __restrict__ qe, const float* __restrict__ ke,
    const float* __restrict__ wo, const float* __restrict__ bo,
    float* __restrict__ out)
{
    __shared__ __align__(16) unsigned LDSu[14664];
    unsigned* A2s = LDSu;
    unsigned* B2s = LDSu + 4096;
    unsigned* M2s = LDSu + 8192;
    unsigned* E2s = LDSu + 12288;             // [16][132]
    unsigned* G2s = LDSu + 14400;             // [2][132]

    const int t = threadIdx.x;
    const int blk = blockIdx.x;
    const int b = blk >> 6;
    const int q0 = (blk & 63) * 2;

    // ---- issue ke row loads FIRST (E-phase consumes these earliest) ----
    const float4* kerow = (const float4*)(ke + ((size_t)b * LK + t) * ET);
    float4 kr[8];
    #pragma unroll
    for (int h = 0; h < 8; ++h) kr[h] = kerow[h];

    // ---- then issue panel loads into registers (stay in flight during E) ----
    uint4 pa[4], pb[4], pm[4];
    {
        const uint4* Ag = (const uint4*)(A2g + (size_t)b * 4096);
        const uint4* Bg = (const uint4*)(B2g + (size_t)b * 4096);
        const uint4* Mg = (const uint4*)(M2g + (size_t)b * 4096);
        #pragma unroll
        for (int i = 0; i < 4; ++i) {
            const int idx = i * 256 + t;
            pa[i] = Ag[idx]; pb[i] = Bg[idx]; pm[i] = Mg[idx];
        }
    }

    // ---- E/G phase: thread = k; only global inputs (no LDS deps) ----
    {
        const float ktk = ktt[b * LK + t];
        const float wd = w_decay[0];
        unsigned short* E2u = (unsigned short*)E2s;   // row stride 264 u16
        unsigned short* G2u = (unsigned short*)G2s;
        #pragma unroll
        for (int h = 0; h < 8; ++h) {                 // fold 1/sqrt(4)=0.5 into k
            kr[h].x *= 0.5f; kr[h].y *= 0.5f; kr[h].z *= 0.5f; kr[h].w *= 0.5f;
        }
        #pragma unroll
        for (int q = 0; q < 2; ++q) {
            const float dt = qtt[b * LQ + q0 + q] - ktk;
            G2u[q * 264 + t] = h16(dt / fmaf(wd, dt, 1.0f));
            const float4* qrow = (const float4*)(qe + ((size_t)b * LQ + q0 + q) * ET);
            #pragma unroll
            for (int h = 0; h < 8; ++h) {
                const float4 qq = qrow[h];            // uniform addr -> broadcast
                float sc = qq.x * kr[h].x;
                sc = fmaf(qq.y, kr[h].y, sc);
                sc = fmaf(qq.z, kr[h].z, sc);
                sc = fmaf(qq.w, kr[h].w, sc);
                E2u[(q * 8 + h) * 264 + t] = h16(__expf(sc));  // |sc| << 1
            }
        }
    }

    // ---- write panels to LDS (panels arrived during E compute) ----
    #pragma unroll
    for (int i = 0; i < 4; ++i) {
        const int idx = i * 256 + t;
        ((uint4*)A2s)[idx] = pa[i];
        ((uint4*)B2s)[idx] = pb[i];
        ((uint4*)M2s)[idx] = pm[i];
    }
    __syncthreads();   // single barrier before main loop

    // ---- main loop: thread = (ks 0..7, hg 0..3 -> h{2hg,2hg+1}, dg 0..7) ----
    const int ks = t >> 5, hg = (t >> 3) & 3, dg = t & 7;
    const int hb = 2 * hg;
    float accN[2][2][4] = {{{0}}}, accD[2][2][4] = {{{0}}};
    {
        const unsigned* Eb = E2s + ks * 16;
        const unsigned* Gb = G2s + ks * 16;
        const unsigned* Ab = A2s + ks * 512 + dg * 4;
        const unsigned* Bb = B2s + ks * 512 + dg * 4;
        const unsigned* Mb = M2s + ks * 512 + dg * 4;
        #pragma unroll
        for (int si = 0; si < 4; ++si) {
            unsigned eu[2][2][4];
            uint4 gu[2];
            unsigned au[4][4], bu[4][4], mu_[4][4];
            #pragma unroll
            for (int q = 0; q < 2; ++q) {
                #pragma unroll
                for (int hh = 0; hh < 2; ++hh) {
                    const uint4 v = *(const uint4*)(Eb + (q*8 + hb + hh)*132 + si*4);
                    eu[q][hh][0]=v.x; eu[q][hh][1]=v.y; eu[q][hh][2]=v.z; eu[q][hh][3]=v.w;
                }
                gu[q] = *(const uint4*)(Gb + q*132 + si*4);
            }
            #pragma unroll
            for (int j = 0; j < 4; ++j) {
                const uint4 a  = *(const uint4*)(Ab + (si*4 + j)*32);
                const uint4 bb = *(const uint4*)(Bb + (si*4 + j)*32);
                const uint4 m  = *(const uint4*)(Mb + (si*4 + j)*32);
                au[j][0]=a.x; au[j][1]=a.y; au[j][2]=a.z; au[j][3]=a.w;
                bu[j][0]=bb.x; bu[j][1]=bb.y; bu[j][2]=bb.z; bu[j][3]=bb.w;
                mu_[j][0]=m.x; mu_[j][1]=m.y; mu_[j][2]=m.z; mu_[j][3]=m.w;
            }
            #pragma unroll
            for (int q = 0; q < 2; ++q) {
                const unsigned gq[4] = {gu[q].x, gu[q].y, gu[q].z, gu[q].w};
                #pragma unroll
                for (int hh = 0; hh < 2; ++hh)
                #pragma unroll
                for (int j = 0; j < 4; ++j) {
                    const h2 e2  = bch(eu[q][hh][j]);
                    const h2 eg2 = e2 * bch(gq[j]);       // v_pk_mul_f16
                    #pragma unroll
                    for (int dd = 0; dd < 4; ++dd) {
                        accN[q][hh][dd] = dot2(e2,  bch(au[j][dd]),  accN[q][hh][dd]);
                        accN[q][hh][dd] = dot2(eg2, bch(bu[j][dd]),  accN[q][hh][dd]);
                        accD[q][hh][dd] = dot2(e2,  bch(mu_[j][dd]), accD[q][hh][dd]);
                    }
                }
            }
        }
    }
    __syncthreads();

    // ---- cross-ks partials (alias over dead A2s/B2s) ----
    float* REDN = (float*)A2s;    // 4096 f
    float* REDD = (float*)B2s;    // 4096 f
    float* XSH  = (float*)M2s;    // 512 f
    #pragma unroll
    for (int q = 0; q < 2; ++q)
    #pragma unroll
    for (int hh = 0; hh < 2; ++hh) {
        const int c = (q * 8 + hb + hh) * 32 + dg * 4;
        *(float4*)&REDN[ks * 512 + c] =
            make_float4(accN[q][hh][0], accN[q][hh][1], accN[q][hh][2], accN[q][hh][3]);
        *(float4*)&REDD[ks * 512 + c] =
            make_float4(accD[q][hh][0], accD[q][hh][1], accD[q][hh][2], accD[q][hh][3]);
    }
    __syncthreads();

    // ---- reduce over ks + divide ----
    if (t < 128) {
        float4 n = make_float4(0.f,0.f,0.f,0.f), d = make_float4(0.f,0.f,0.f,0.f);
        #pragma unroll
        for (int s = 0; s < 8; ++s) {
            const float4 nn = *(const float4*)&REDN[s * 512 + t * 4];
            const float4 dd = *(const float4*)&REDD[s * 512 + t * 4];
            n.x += nn.x; n.y += nn.y; n.z += nn.z; n.w += nn.w;
            d.x += dd.x; d.y += dd.y; d.z += dd.z; d.w += dd.w;
        }
        float4 x;
        x.x = n.x / fmaxf(d.x, 1e-30f);
        x.y = n.y / fmaxf(d.y, 1e-30f);
        x.z = n.z / fmaxf(d.z, 1e-30f);
        x.w = n.w / fmaxf(d.w, 1e-30f);
        *(float4*)&XSH[t * 4] = x;
    }
    __syncthreads();

    // ---- epilogue: thread = (q, j4 0..15, cs 0..7); float4 wo loads ----
    {
        const int q  = t >> 7;
        const int j4 = (t >> 3) & 15;
        const int cs = t & 7;
        const float* xq = XSH + q * 256;
        float4 a4 = make_float4(0.f, 0.f, 0.f, 0.f);
        #pragma unroll 8
        for (int cc = 0; cc < 32; ++cc) {
            const int c = cs * 32 + ((cc + 4 * cs) & 31);   // bank-skewed
            const float xv = xq[c];
            const float4 wv = *(const float4*)&wo[c * NH + j4 * 4];
            a4.x = fmaf(xv, wv.x, a4.x);
            a4.y = fmaf(xv, wv.y, a4.y);
            a4.z = fmaf(xv, wv.z, a4.z);
            a4.w = fmaf(xv, wv.w, a4.w);
        }
        #pragma unroll
        for (int off = 1; off < 8; off <<= 1) {
            a4.x += __shfl_xor(a4.x, off);
            a4.y += __shfl_xor(a4.y, off);
            a4.z += __shfl_xor(a4.z, off);
            a4.w += __shfl_xor(a4.w, off);
        }
        if (cs == 0) {
            const float4 bv = *(const float4*)&bo[j4 * 4];
            float4 o;
            o.x = a4.x + bv.x; o.y = a4.y + bv.y;
            o.z = a4.z + bv.z; o.w = a4.w + bv.w;
            *(float4*)&out[((size_t)b * LQ + q0 + q) * NH + j4 * 4] = o;
        }
    }
}

extern "C" void kernel_launch(void* const* d_in, const int* in_sizes, int n_in,
                              void* d_out, int out_size, void* d_ws, size_t ws_size,
                              hipStream_t stream) {
    const float* qtt      = (const float*)d_in[0];
    const float* ktt      = (const float*)d_in[1];
    const float* value    = (const float*)d_in[2];
    const int*   emb_mask = (const int*)  d_in[3];
    const float* w_time   = (const float*)d_in[4];
    const float* b_time   = (const float*)d_in[5];
    const float* w_per    = (const float*)d_in[6];
    const float* b_per    = (const float*)d_in[7];
    const float* w_decay  = (const float*)d_in[8];
    const float* vt_w1    = (const float*)d_in[9];
    const float* vt_b1    = (const float*)d_in[10];
    const float* ln_g     = (const float*)d_in[11];
    const float* ln_b     = (const float*)d_in[12];
    const float* vt_w2    = (const float*)d_in[13];
    const float* vt_b2    = (const float*)d_in[14];
    const float* wq       = (const float*)d_in[15];
    const float* bq       = (const float*)d_in[16];
    const float* wk       = (const float*)d_in[17];
    const float* bk       = (const float*)d_in[18];
    const float* wo       = (const float*)d_in[19];
    const float* bo       = (const float*)d_in[20];
    float* out = (float*)d_out;

    unsigned* wsu = (unsigned*)d_ws;
    unsigned* A2g = wsu;               // 32768 u (1024 k2 x 32 d)
    unsigned* B2g = wsu + 32768;
    unsigned* M2g = wsu + 65536;
    float*    qew = (float*)(wsu + 98304);   // 32768 f
    float*    kew = (float*)(wsu + 131072);  // 65536 f

    hipLaunchKernelGGL(prep_kernel, dim3(896), dim3(256), 0, stream,
                       qtt, ktt, value, emb_mask, w_time, b_time, w_per, b_per,
                       vt_w1, vt_b1, ln_g, ln_b, vt_w2, vt_b2,
                       wq, bq, wk, bk, A2g, B2g, M2g, qew, kew);

    hipLaunchKernelGGL(attn_kernel, dim3(512), dim3(256), 0, stream,
                       qtt, ktt, w_decay, A2g, B2g, M2g, qew, kew, wo, bo, out);
}